// Round 13
// baseline (673.147 us; speedup 1.0000x reference)
//
#include <hip/hip_runtime.h>
#include <hip/hip_bf16.h>
#include <hip/hip_fp16.h>
#include <math.h>

// GatedAttention R28: revert flash to R26 (R27's 2-wave reg-squeeze spilled:
// VGPR 128+128acc = cap, WRITE +6.4MB scratch, both pipes fell, 112->156us) +
// combiner rewrite: old grid (16,8,8) re-read Opart 8x (537MB) + F 8x (134MB);
// new: each thread owns q and all 128 outputs (acc[128] unrolled), grid (16,8),
// Opart/F read ONCE (~200MB), weights via pre-transposed cwT[c][256] so the
// unrolled j-loop is two contiguous wave-uniform 512B blocks (s_load runs).
// transform_cw_k added (tiny). Rest = R26 (conv3 OYB=4, frag-ordered flash).

#define PI_F 3.1415926f

typedef __attribute__((ext_vector_type(8))) short short8;
typedef __attribute__((ext_vector_type(4))) float f32x4;
typedef _Float16 half8 __attribute__((ext_vector_type(8)));
typedef __attribute__((ext_vector_type(4))) unsigned short u16x4;
typedef unsigned short ushort_t;

__device__ __forceinline__ ushort_t f2bf(float x) {
    unsigned u = __float_as_uint(x);
    unsigned r = (u + 0x7FFFu + ((u >> 16) & 1u)) >> 16;
    return (ushort_t)r;
}
__device__ __forceinline__ void split16(float x, ushort_t& h, ushort_t& l) {
    __half hh = __float2half(x);
    h = __half_as_ushort(hh);
    l = __half_as_ushort(__float2half(x - __half2float(hh)));
}
__device__ __forceinline__ ushort_t f2h(float x) {
    return __half_as_ushort(__float2half(x));
}
__device__ __forceinline__ int swz(int r, int c) {
    return ((c ^ r ^ (r >> 2)) & 3) << 3;
}

// ---------------- weight transform: OIHW fp32 -> [ky*kx][oc][ic] fp16 hi/lo --------
__global__ __launch_bounds__(256) void transform_w_k(
    const float* __restrict__ w, ushort_t* __restrict__ Wh, ushort_t* __restrict__ Wl,
    int Cout, int Cin, int KK)
{
    int idx = blockIdx.x * 256 + threadIdx.x;
    int N = Cout * Cin * KK;
    if (idx >= N) return;
    int oc = idx / (Cin * KK);
    int rem = idx - oc * (Cin * KK);
    int ic = rem / KK;
    int t = rem - ic * KK;
    float v = w[idx];
    long dst = ((long)t * Cout + oc) * Cin + ic;
    split16(v, Wh[dst], Wl[dst]);
}

// ------- conv1 weight transform: [32][4][7][7] -> [7 ky][32 oc][32 k=kx*4+ic] ------
__global__ __launch_bounds__(256) void transform_w1_k(
    const float* __restrict__ w, ushort_t* __restrict__ Wh, ushort_t* __restrict__ Wl)
{
    int idx = blockIdx.x * 256 + threadIdx.x;
    if (idx >= 7 * 32 * 32) return;
    int ky = idx / 1024;
    int rem = idx - ky * 1024;
    int oc = rem >> 5;
    int k = rem & 31;
    float v = 0.f;
    if (k < 28) {
        int kx = k >> 2, ic = k & 3;
        v = w[((oc * 4 + ic) * 7 + ky) * 7 + kx];
    }
    split16(v, Wh[idx], Wl[idx]);
}

// ------- combiner weight transform: cw[o][256] -> cwT[c][ a:o | f:128+o ] ---------
__global__ __launch_bounds__(256) void transform_cw_k(
    const float* __restrict__ cw, float* __restrict__ cwT)
{
    int idx = blockIdx.x * 256 + threadIdx.x;
    if (idx >= 16384) return;
    int o = idx >> 7, c = idx & 127;
    cwT[c * 256 + o]       = cw[o * 256 + c];
    cwT[c * 256 + 128 + o] = cw[o * 256 + 128 + c];
}

// ------- prep conv1 input: reflect-pad(3) -> channel-last [8][262][262][4] fp16 h --
__global__ __launch_bounds__(256) void prep_in_k(
    const float* __restrict__ imgs, const float* __restrict__ masks,
    ushort_t* __restrict__ Xh)
{
    const int iy = blockIdx.x, b = blockIdx.y;
    int sy = iy - 3; if (sy < 0) sy = -sy; if (sy >= 256) sy = 510 - sy;
    const int rb = sy << 8;
    const float* i0 = imgs + (long)b * 3 * 65536;
    const float* mk = masks + (long)b * 65536;
    for (int x = threadIdx.x; x < 262; x += 256) {
        int sx = x - 3; if (sx < 0) sx = -sx; if (sx >= 256) sx = 510 - sx;
        u16x4 hv;
        hv[0] = f2h(i0[rb + sx]);
        hv[1] = f2h(i0[65536 + rb + sx]);
        hv[2] = f2h(i0[131072 + rb + sx]);
        hv[3] = f2h(mk[rb + sx]);
        long o = ((long)(b * 262 + iy) * 262 + x) * 4;
        *(u16x4*)&Xh[o] = hv;
    }
}

// ------- conv1 MFMA (2-term): 32 oc x 64 px per block -----------
__global__ __launch_bounds__(256) void conv1_mfma_k(
    const ushort_t* __restrict__ Xinh,
    const ushort_t* __restrict__ W1h, const ushort_t* __restrict__ W1l,
    const float* __restrict__ bias, ushort_t* __restrict__ Oh)
{
    const int tid = threadIdx.x, lane = tid & 63, wid = tid >> 6;
    const int wm = wid & 1, wn = wid >> 1, l15 = lane & 15, quad = lane >> 4;
    const int ox0 = blockIdx.x * 64;
    const int oy = blockIdx.y, b = blockIdx.z;
    f32x4 acc[2];
    acc[0] = (f32x4){0.f, 0.f, 0.f, 0.f};
    acc[1] = (f32x4){0.f, 0.f, 0.f, 0.f};
#pragma unroll
    for (int ky = 0; ky < 7; ++ky) {
        long wo = (long)(ky * 32 + wm * 16 + l15) * 32 + quad * 8;
        half8 Ah = *(const half8*)&W1h[wo];
        half8 Al = *(const half8*)&W1l[wo];
        long xrow = ((long)(b * 262 + oy + ky) * 262 + ox0) * 4;
#pragma unroll
        for (int ni = 0; ni < 2; ++ni) {
            long xo = xrow + (wn * 32 + ni * 16 + l15) * 4 + quad * 8;
            half8 Bh = *(const half8*)&Xinh[xo];
            acc[ni] = __builtin_amdgcn_mfma_f32_16x16x32_f16(Ah, Bh, acc[ni], 0, 0, 0);
            acc[ni] = __builtin_amdgcn_mfma_f32_16x16x32_f16(Al, Bh, acc[ni], 0, 0, 0);
        }
    }
    const int ocf = wm * 16 + quad * 4;
    float4 bv = *(const float4*)&bias[ocf];
#pragma unroll
    for (int ni = 0; ni < 2; ++ni) {
        int n = ox0 + wn * 32 + ni * 16 + l15;
        u16x4 hv;
        hv[0] = f2h(fmaxf(acc[ni][0] + bv.x, 0.f));
        hv[1] = f2h(fmaxf(acc[ni][1] + bv.y, 0.f));
        hv[2] = f2h(fmaxf(acc[ni][2] + bv.z, 0.f));
        hv[3] = f2h(fmaxf(acc[ni][3] + bv.w, 0.f));
        long o = ((long)(b * 260 + oy + 2) * 260 + n + 2) * 32 + ocf;
        *(u16x4*)&Oh[o] = hv;
    }
}

// ------- pad-fill for channel-last reflect-padded h-only buffers ----
__global__ __launch_bounds__(256) void pad_cl_k(
    ushort_t* __restrict__ Xh, int Hp, int Wp, int PAD, int C, int H, int W)
{
    const int iy = blockIdx.x, b = blockIdx.y;
    int t = iy - PAD; if (t < 0) t = -t; if (t >= H) t = 2 * H - 2 - t;
    const int iys = t + PAD;
    const long rowd = ((long)(b * Hp + iy) * Wp) * C;
    const long rows = ((long)(b * Hp + iys) * Wp) * C;
    const int nch = Wp * (C >> 3);
    for (int idx = threadIdx.x; idx < nch; idx += 256) {
        int x = idx / (C >> 3);
        int cg = (idx - x * (C >> 3)) << 3;
        int t2 = x - PAD; if (t2 < 0) t2 = -t2; if (t2 >= W) t2 = 2 * W - 2 - t2;
        int xs = t2 + PAD;
        if (xs == x && iys == iy) continue;
        *(int4*)&Xh[rowd + (long)x * C + cg] = *(const int4*)&Xh[rows + (long)xs * C + cg];
    }
}

// ------- MFMA conv (2-term split), swizzled LDS, de-interleave for S=2 ----
template<int K, int S, int CIN, int CSTG, int MT, int NPX, bool WRITE_CL>
__global__ __launch_bounds__(256, 2) void conv_mfma_k(
    const ushort_t* __restrict__ Xh,
    const ushort_t* __restrict__ Wh, const ushort_t* __restrict__ Wl,
    const float* __restrict__ bias,
    int Hp, int Wp, int CoutT,
    ushort_t* __restrict__ Oh, int Hpn, int Wpn, int NP,
    float* __restrict__ Ofp)
{
    constexpr int WS = (NPX - 1) * S + K;
    constexpr int WS2 = (WS + 1) / 2;
    constexpr int MF = MT / 32;
    constexpr int NF = NPX / 32;
    __shared__ ushort_t Bsh[WS * CSTG];
    __shared__ ushort_t Ash[K * MT * CSTG];
    __shared__ ushort_t Asl[K * MT * CSTG];
    const int tid = threadIdx.x, lane = tid & 63, wid = tid >> 6;
    const int wm = wid & 1, wn = wid >> 1, l15 = lane & 15, quad = lane >> 4;
    const int bx = blockIdx.x, oy = blockIdx.y;
    const int NOC = CoutT / MT;
    const int ocg = blockIdx.z % NOC, b = blockIdx.z / NOC;
    const int ox0 = bx * NPX;

    f32x4 acc[MF][NF];
#pragma unroll
    for (int mi = 0; mi < MF; ++mi)
#pragma unroll
        for (int ni = 0; ni < NF; ++ni) acc[mi][ni] = (f32x4){0.f, 0.f, 0.f, 0.f};

#pragma unroll
    for (int ky = 0; ky < K; ++ky) {
        const long rowoff = ((long)(b * Hp + oy * S + ky) * Wp + ox0 * S) * CIN;
        for (int cs = 0; cs < CIN; cs += CSTG) {
            __syncthreads();
            constexpr int NCH = WS * CSTG / 8;
#pragma unroll
            for (int it = 0; it < (NCH + 255) / 256; ++it) {
                int flat = tid + it * 256;
                if (flat < NCH) {
                    int e0 = flat * 8;
                    int x = e0 / CSTG;
                    int cpos = (e0 - x * CSTG) >> 3;
                    int xs = (S == 1) ? x : ((x >> 1) + (x & 1) * WS2);
                    *(int4*)&Bsh[xs * CSTG + swz(xs, cpos)] =
                        *(const int4*)&Xh[rowoff + (long)x * CIN + cs + cpos * 8];
                }
            }
            constexpr int NW = K * MT * CSTG / 8;
#pragma unroll
            for (int it = 0; it < (NW + 255) / 256; ++it) {
                int flat = tid + it * 256;
                if (flat < NW) {
                    int e0 = flat * 8;
                    int kx = e0 / (MT * CSTG);
                    int rem = e0 - kx * MT * CSTG;
                    int oc = rem / CSTG;
                    int cpos = (rem - oc * CSTG) >> 3;
                    int arow = kx * MT + oc;
                    int dst = arow * CSTG + swz(arow, cpos);
                    long src = ((long)((ky * K + kx) * CoutT + ocg * MT + oc)) * CIN + cs + cpos * 8;
                    *(int4*)&Ash[dst] = *(const int4*)&Wh[src];
                    *(int4*)&Asl[dst] = *(const int4*)&Wl[src];
                }
            }
            __syncthreads();
#pragma unroll
            for (int kx = 0; kx < K; ++kx) {
                half8 Ah[MF], Al[MF], Bh[NF];
#pragma unroll
                for (int mi = 0; mi < MF; ++mi) {
                    int arow = kx * MT + wm * (MT / 2) + mi * 16 + l15;
                    int ao = arow * CSTG + swz(arow, quad);
                    Ah[mi] = *(const half8*)&Ash[ao];
                    Al[mi] = *(const half8*)&Asl[ao];
                }
#pragma unroll
                for (int ni = 0; ni < NF; ++ni) {
                    int m = wn * (NPX / 2) + ni * 16 + l15;
                    int xs = (S == 1) ? (m + kx) : (m + (kx >> 1) + (kx & 1) * WS2);
                    Bh[ni] = *(const half8*)&Bsh[xs * CSTG + swz(xs, quad)];
                }
#pragma unroll
                for (int mi = 0; mi < MF; ++mi)
#pragma unroll
                    for (int ni = 0; ni < NF; ++ni) {
                        acc[mi][ni] = __builtin_amdgcn_mfma_f32_16x16x32_f16(Ah[mi], Bh[ni], acc[mi][ni], 0, 0, 0);
                        acc[mi][ni] = __builtin_amdgcn_mfma_f32_16x16x32_f16(Al[mi], Bh[ni], acc[mi][ni], 0, 0, 0);
                    }
            }
        }
    }
#pragma unroll
    for (int ni = 0; ni < NF; ++ni) {
        const int n = ox0 + wn * (NPX / 2) + ni * 16 + l15;
#pragma unroll
        for (int mi = 0; mi < MF; ++mi) {
            const int ocf = ocg * MT + wm * (MT / 2) + mi * 16 + quad * 4;
            float4 bv = *(const float4*)&bias[ocf];
            float v0 = fmaxf(acc[mi][ni][0] + bv.x, 0.f);
            float v1 = fmaxf(acc[mi][ni][1] + bv.y, 0.f);
            float v2 = fmaxf(acc[mi][ni][2] + bv.z, 0.f);
            float v3 = fmaxf(acc[mi][ni][3] + bv.w, 0.f);
            if (WRITE_CL) {
                long o = ((long)(b * Hpn + oy + NP) * Wpn + n + NP) * CoutT + ocf;
                u16x4 hv;
                hv[0] = f2h(v0); hv[1] = f2h(v1); hv[2] = f2h(v2); hv[3] = f2h(v3);
                *(u16x4*)&Oh[o] = hv;
            } else {
                long o = ((long)(b * CoutT + ocf) << 12) + (oy << 6) + n;
                Ofp[o] = v0;
                Ofp[o + 4096] = v1;
                Ofp[o + 8192] = v2;
                Ofp[o + 12288] = v3;
            }
        }
    }
}

// ------- conv3 dedicated: K5 S1 CIN64 CSTG32 MT64 NPX128, OYB=4 rows/block ----
__global__ __launch_bounds__(256, 2) void conv3_mfma_k(
    const ushort_t* __restrict__ Xh,
    const ushort_t* __restrict__ Wh, const ushort_t* __restrict__ Wl,
    const float* __restrict__ bias, ushort_t* __restrict__ Oh)
{
    __shared__ ushort_t Bsh[4][132 * 32];   // 33792 B
    __shared__ ushort_t Ash[5 * 64 * 32];   // 20480 B
    __shared__ ushort_t Asl[5 * 64 * 32];   // 20480 B
    const int tid = threadIdx.x, lane = tid & 63, wid = tid >> 6;
    const int wm = wid & 1, wn = wid >> 1, l15 = lane & 15, quad = lane >> 4;
    const int oy0 = blockIdx.y * 4;
    const int ocg = blockIdx.z & 1, b = blockIdx.z >> 1;

    f32x4 acc[4][2][4];
#pragma unroll
    for (int oyi = 0; oyi < 4; ++oyi)
#pragma unroll
        for (int mi = 0; mi < 2; ++mi)
#pragma unroll
            for (int ni = 0; ni < 4; ++ni) acc[oyi][mi][ni] = (f32x4){0.f, 0.f, 0.f, 0.f};

    for (int csi = 0; csi < 2; ++csi) {
        const int cb = csi * 32;
        for (int flat = tid; flat < 3 * 528; flat += 256) {
            int r0 = flat / 528;
            int rem = flat - r0 * 528;
            int e0 = rem * 8;
            int x = e0 >> 5;
            int cpos = (e0 & 31) >> 3;
            *(int4*)&Bsh[r0][x * 32 + swz(x, cpos)] =
                *(const int4*)&Xh[((long)(b * 132 + oy0 + r0) * 132 + x) * 64 + cb + cpos * 8];
        }
        for (int ky = 0; ky < 5; ++ky) {
            {
                const int row = oy0 + ky + 3;
                const int slot = (ky + 3) & 3;
                for (int flat = tid; flat < 528; flat += 256) {
                    int e0 = flat * 8;
                    int x = e0 >> 5;
                    int cpos = (e0 & 31) >> 3;
                    *(int4*)&Bsh[slot][x * 32 + swz(x, cpos)] =
                        *(const int4*)&Xh[((long)(b * 132 + row) * 132 + x) * 64 + cb + cpos * 8];
                }
            }
            for (int flat = tid; flat < 1280; flat += 256) {
                int e0 = flat * 8;
                int kx = e0 >> 11;
                int rem = e0 & 2047;
                int oc = rem >> 5;
                int cpos = (rem & 31) >> 3;
                int arow = kx * 64 + oc;
                int dst = arow * 32 + swz(arow, cpos);
                long src = ((long)((ky * 5 + kx) * 128 + ocg * 64 + oc)) * 64 + cb + cpos * 8;
                *(int4*)&Ash[dst] = *(const int4*)&Wh[src];
                *(int4*)&Asl[dst] = *(const int4*)&Wl[src];
            }
            __syncthreads();
#pragma unroll
            for (int kx = 0; kx < 5; ++kx) {
                half8 Ah[2], Al[2];
#pragma unroll
                for (int mi = 0; mi < 2; ++mi) {
                    int arow = kx * 64 + wm * 32 + mi * 16 + l15;
                    int ao = arow * 32 + swz(arow, quad);
                    Ah[mi] = *(const half8*)&Ash[ao];
                    Al[mi] = *(const half8*)&Asl[ao];
                }
#pragma unroll
                for (int oyi = 0; oyi < 4; ++oyi) {
                    const int slot = (ky + oyi) & 3;
                    half8 Bh[4];
#pragma unroll
                    for (int ni = 0; ni < 4; ++ni) {
                        int xs = wn * 64 + ni * 16 + l15 + kx;
                        Bh[ni] = *(const half8*)&Bsh[slot][xs * 32 + swz(xs, quad)];
                    }
#pragma unroll
                    for (int mi = 0; mi < 2; ++mi)
#pragma unroll
                        for (int ni = 0; ni < 4; ++ni) {
                            acc[oyi][mi][ni] = __builtin_amdgcn_mfma_f32_16x16x32_f16(Ah[mi], Bh[ni], acc[oyi][mi][ni], 0, 0, 0);
                            acc[oyi][mi][ni] = __builtin_amdgcn_mfma_f32_16x16x32_f16(Al[mi], Bh[ni], acc[oyi][mi][ni], 0, 0, 0);
                        }
                }
            }
            __syncthreads();
        }
    }
    const int ocf = ocg * 64 + wm * 32 + quad * 4;
#pragma unroll
    for (int oyi = 0; oyi < 4; ++oyi) {
        const int oy = oy0 + oyi;
#pragma unroll
        for (int ni = 0; ni < 4; ++ni) {
            const int n = wn * 64 + ni * 16 + l15;
#pragma unroll
            for (int mi = 0; mi < 2; ++mi) {
                const int oc4 = ocf + mi * 16;
                float4 bv = *(const float4*)&bias[oc4];
                u16x4 hv;
                hv[0] = f2h(fmaxf(acc[oyi][mi][ni][0] + bv.x, 0.f));
                hv[1] = f2h(fmaxf(acc[oyi][mi][ni][1] + bv.y, 0.f));
                hv[2] = f2h(fmaxf(acc[oyi][mi][ni][2] + bv.z, 0.f));
                hv[3] = f2h(fmaxf(acc[oyi][mi][ni][3] + bv.w, 0.f));
                long o = ((long)(b * 130 + oy + 1) * 130 + n + 1) * 128 + oc4;
                *(u16x4*)&Oh[o] = hv;
            }
        }
    }
}

// -------- conv5 (256->1, K3 S1 P1) + relu + gate ----------
__global__ __launch_bounds__(256) void conv5_gate_k(
    const float* __restrict__ s4, const float* __restrict__ w,
    const float* __restrict__ bias, float* __restrict__ gate)
{
    const int tid = threadIdx.x;
    const int lane = tid & 63, g = tid >> 6;
    const int oy = blockIdx.x, b = blockIdx.y;
    int ixo[3], iyo[3];
#pragma unroll
    for (int k = 0; k < 3; ++k) {
        int ix = lane + k - 1; if (ix < 0) ix = -ix; if (ix >= 64) ix = 126 - ix;
        int iy = oy + k - 1; if (iy < 0) iy = -iy; if (iy >= 64) iy = 126 - iy;
        ixo[k] = ix; iyo[k] = iy << 6;
    }
    float part = 0.f;
    const float* inb = s4 + ((long)b * 256 + g * 64) * 4096;
    const float* wg = w + g * 64 * 9;
    for (int ic = 0; ic < 64; ++ic) {
        const float* inc = inb + ic * 4096;
        const float* wc = wg + ic * 9;
#pragma unroll
        for (int ky = 0; ky < 3; ++ky)
#pragma unroll
            for (int kx = 0; kx < 3; ++kx)
                part = fmaf(wc[ky * 3 + kx], inc[iyo[ky] + ixo[kx]], part);
    }
    __shared__ float red[4][64];
    red[g][lane] = part;
    __syncthreads();
    if (tid < 64) {
        float s = bias[0] + red[0][tid] + red[1][tid] + red[2][tid] + red[3][tid];
        s = fmaxf(s, 0.f);
        gate[(b << 12) + (oy << 6) + tid] = tanf(PI_F * (tanhf(s) - 0.5f));
    }
}

// ---------------- invn[b][p] = 1/sqrt(sum_c (F+1e-7)^2) ----------------
__global__ __launch_bounds__(256) void invn_k(const float* __restrict__ F, float* __restrict__ invn)
{
    const int p = blockIdx.x * 256 + threadIdx.x;
    const int b = blockIdx.y;
    const float* Fb = F + (long)b * 524288;
    float ss = 0.f;
#pragma unroll 8
    for (int c = 0; c < 128; ++c) {
        float v = Fb[c * 4096 + p] + 1e-7f;
        ss = fmaf(v, v, ss);
    }
    invn[(b << 12) + p] = 1.0f / sqrtf(ss);
}

// -------- prep: Ft16[b][p][c] (for Bq), Vf[b][chunk][ct][lane][8] (PV A-frags),
//          Fa[b][chunk][sub*4+cs][lane][8] (QK A-frags, permuted rows baked in). ---
__global__ __launch_bounds__(256) void prep_bf16_k(
    const float* __restrict__ F, ushort_t* __restrict__ Vf,
    ushort_t* __restrict__ Fa, ushort_t* __restrict__ Ft16)
{
    __shared__ float Ls[128][65];
    const int tid = threadIdx.x;
    const int lane = tid & 63, wv = tid >> 6;
    const int p0 = blockIdx.x * 64, b = blockIdx.y;
#pragma unroll 8
    for (int cc = 0; cc < 32; ++cc) {
        int c = wv * 32 + cc;
        long idx = ((long)b * 128 + c) * 4096 + p0 + lane;
        Ls[c][lane] = F[idx];
    }
    __syncthreads();
    // Ft16 (p-major) for Bq
#pragma unroll 8
    for (int i = 0; i < 32; ++i) {
        int flat = tid + 256 * i;
        int c = flat & 127, pl_ = flat >> 7;
        Ft16[((long)b * 4096 + p0 + pl_) * 128 + c] = f2bf(Ls[c][pl_]);
    }
    const int chunk0 = blockIdx.x * 2;
    // Vf: frag (ct, lane=(quad<<4)|l15) elem e -> F[b][ct*16+l15][chunk*32+quad*8+e]
#pragma unroll
    for (int s = tid; s < 1024; s += 256) {
        int ck = s >> 9, rem = s & 511;
        int ct = rem >> 6, ln = rem & 63;
        int c = ct * 16 + (ln & 15);
        int pl = ck * 32 + (ln >> 4) * 8;
        ushort_t tmp[8];
#pragma unroll
        for (int e = 0; e < 8; ++e) tmp[e] = f2bf(Ls[c][pl + e]);
        *(short8*)&Vf[(((long)(b * 128 + chunk0 + ck) * 8 + ct) * 64 + ln) * 8] = *(short8*)tmp;
    }
    // Fa: frag (f=sub*4+cs, lane) elem e ->
    //   F[b][(f&3)*32+(ln>>4)*8+e][chunk*32 + ((l15&12)<<1)+(l15&3) + (f>>2)*4]
#pragma unroll
    for (int s = tid; s < 1024; s += 256) {
        int ck = s >> 9, rem = s & 511;
        int f = rem >> 6, ln = rem & 63;
        int l15_ = ln & 15;
        int c0 = (f & 3) * 32 + (ln >> 4) * 8;
        int pl = ck * 32 + ((l15_ & 12) << 1) + (l15_ & 3) + (f >> 2) * 4;
        ushort_t tmp[8];
#pragma unroll
        for (int e = 0; e < 8; ++e) tmp[e] = f2bf(Ls[c0 + e][pl]);
        *(short8*)&Fa[(((long)(b * 128 + chunk0 + ck) * 8 + f) * 64 + ln) * 8] = *(short8*)tmp;
    }
}

// -------- flash attention (R26): q=64, 1 wave, reg-dbuf, fragment-ordered loads ---
__global__ __launch_bounds__(64, 1) void flash_attn_k(
    const ushort_t* __restrict__ Ft16, const ushort_t* __restrict__ Vf,
    const ushort_t* __restrict__ Fa,
    const float* __restrict__ invn, const float* __restrict__ gate,
    float* __restrict__ Opart, float* __restrict__ lpart)
{
    const int lane = threadIdx.x & 63;
    const int l15 = lane & 15, quad = lane >> 4;
    const int b = blockIdx.x;
    const int qb = blockIdx.y & 63, ks = blockIdx.y >> 6;
    const int q0 = qb * 64;
    const int bp = b << 12;
    const ushort_t* Ftb = Ft16 + (long)b * 4096 * 128;
    const ushort_t* FaB = Fa + (long)b * 128 * 8 * 512;
    const ushort_t* VfB = Vf + (long)b * 128 * 8 * 512;

    short8 Bq[4][4];
#pragma unroll
    for (int ni = 0; ni < 4; ++ni)
#pragma unroll
        for (int cs = 0; cs < 4; ++cs)
            Bq[ni][cs] = *(const short8*)&Ftb[(long)(q0 + ni * 16 + l15) * 128 + cs * 32 + quad * 8];

    f32x4 O[8][4];
#pragma unroll
    for (int ct = 0; ct < 8; ++ct)
#pragma unroll
        for (int ni = 0; ni < 4; ++ni) O[ct][ni] = (f32x4){0.f, 0.f, 0.f, 0.f};
    float l_acc[4] = {0.f, 0.f, 0.f, 0.f};

    union BeU { short8 v; __hip_bfloat162 h[4]; };
    const int p_beg = ks * 1024;
    const int ck_beg = ks * 32;
    const long lane8 = (long)lane * 8;

    short8 Ap[2][2][4];
    short8 Va[2][8];
    float4 ivb[2][2], gtb[2][2];

    {
        const long fb = (long)(ck_beg) * 4096;
#pragma unroll
        for (int sub = 0; sub < 2; ++sub) {
#pragma unroll
            for (int cs = 0; cs < 4; ++cs)
                Ap[0][sub][cs] = *(const short8*)&FaB[fb + (long)(sub * 4 + cs) * 512 + lane8];
            ivb[0][sub] = *(const float4*)&invn[bp + p_beg + quad * 8 + sub * 4];
            gtb[0][sub] = *(const float4*)&gate[bp + p_beg + quad * 8 + sub * 4];
        }
#pragma unroll
        for (int ct = 0; ct < 8; ++ct)
            Va[0][ct] = *(const short8*)&VfB[fb + (long)ct * 512 + lane8];
    }

#pragma unroll 2
    for (int t = 0; t < 32; ++t) {
        const int cur = t & 1, nxt = cur ^ 1;
        if (t + 1 < 32) {
            const int p1 = p_beg + (t + 1) * 32;
            const long fb = (long)(ck_beg + t + 1) * 4096;
#pragma unroll
            for (int sub = 0; sub < 2; ++sub) {
#pragma unroll
                for (int cs = 0; cs < 4; ++cs)
                    Ap[nxt][sub][cs] = *(const short8*)&FaB[fb + (long)(sub * 4 + cs) * 512 + lane8];
                ivb[nxt][sub] = *(const float4*)&invn[bp + p1 + quad * 8 + sub * 4];
                gtb[nxt][sub] = *(const float4*)&gate[bp + p1 + quad * 8 + sub * 4];
            }
#pragma unroll
            for (int ct = 0; ct < 8; ++ct)
                Va[nxt][ct] = *(const short8*)&VfB[fb + (long)ct * 512 + lane8];
        }
        BeU be[4];
#pragma unroll
        for (int sub = 0; sub < 2; ++sub) {
            f32x4 Sa[4];
#pragma unroll
            for (int ni = 0; ni < 4; ++ni) Sa[ni] = (f32x4){0.f, 0.f, 0.f, 0.f};
#pragma unroll
            for (int cs = 0; cs < 4; ++cs)
#pragma unroll
                for (int ni = 0; ni < 4; ++ni)
                    Sa[ni] = __builtin_amdgcn_mfma_f32_16x16x32_bf16(Ap[cur][sub][cs], Bq[ni][cs], Sa[ni], 0, 0, 0);
            const float4 iv = ivb[cur][sub];
            const float4 gt = gtb[cur][sub];
#pragma unroll
            for (int ni = 0; ni < 4; ++ni) {
                float e0 = __expf(fmaf(Sa[ni][0], iv.x, gt.x));
                float e1 = __expf(fmaf(Sa[ni][1], iv.y, gt.y));
                float e2 = __expf(fmaf(Sa[ni][2], iv.z, gt.z));
                float e3 = __expf(fmaf(Sa[ni][3], iv.w, gt.w));
                be[ni].h[sub * 2]     = __float22bfloat162_rn(make_float2(e0, e1));
                be[ni].h[sub * 2 + 1] = __float22bfloat162_rn(make_float2(e2, e3));
                l_acc[ni] += (e0 + e1) + (e2 + e3);
            }
        }
#pragma unroll
        for (int ct = 0; ct < 8; ++ct)
#pragma unroll
            for (int ni = 0; ni < 4; ++ni)
                O[ct][ni] = __builtin_amdgcn_mfma_f32_16x16x32_bf16(Va[cur][ct], be[ni].v, O[ct][ni], 0, 0, 0);
    }

#pragma unroll
    for (int ni = 0; ni < 4; ++ni) {
        float lt = l_acc[ni];
        lt += __shfl_xor(lt, 16);
        lt += __shfl_xor(lt, 32);
        if (quad == 0)
            lpart[(ks * 8 + b) * 4096 + q0 + ni * 16 + l15] = lt;
    }
    float* Ob = Opart + (long)(ks * 8 + b) * 524288;
#pragma unroll
    for (int ct = 0; ct < 8; ++ct)
#pragma unroll
        for (int ni = 0; ni < 4; ++ni) {
            int c = ct * 16 + quad * 4;
            int q = q0 + ni * 16 + l15;
#pragma unroll
            for (int r = 0; r < 4; ++r)
                Ob[((long)(c + r) << 12) + q] = O[ct][ni][r];
        }
}

// ---------------- combiner (R28): each thread owns q and ALL 128 outputs.
// Opart and F read ONCE (vs 8x); weights from cwT[c][256] (contiguous, scalar). ----
__global__ __launch_bounds__(256) void combiner_k(
    const float* __restrict__ Opart, const float* __restrict__ lpart,
    const float* __restrict__ F, const float* __restrict__ cwT,
    const float* __restrict__ cb, float* __restrict__ out)
{
    const int tid = threadIdx.x;
    const int q = blockIdx.x * 256 + tid;
    const int b = blockIdx.y;
    float lsum = 0.f;
#pragma unroll
    for (int ks = 0; ks < 4; ++ks) lsum += lpart[(ks * 8 + b) * 4096 + q];
    float il = 1.0f / lsum;
    const float* Fb = F + (long)b * 524288 + q;
    float acc[128];
#pragma unroll
    for (int j = 0; j < 128; ++j) acc[j] = cb[j];
    for (int c = 0; c < 128; ++c) {
        float a = 0.f;
#pragma unroll
        for (int ks = 0; ks < 4; ++ks)
            a += Opart[(long)(ks * 8 + b) * 524288 + (long)c * 4096 + q];
        a *= il;
        float f = Fb[(long)c * 4096];
        const float* wc = cwT + c * 256;
#pragma unroll
        for (int j = 0; j < 128; ++j)
            acc[j] = fmaf(wc[j], a, fmaf(wc[128 + j], f, acc[j]));
    }
#pragma unroll
    for (int j = 0; j < 128; ++j)
        out[((long)(b * 128 + j) << 12) + q] = acc[j];
}

// =====================================================================================
extern "C" void kernel_launch(void* const* d_in, const int* in_sizes, int n_in,
                              void* d_out, int out_size, void* d_ws, size_t ws_size,
                              hipStream_t stream)
{
    const float* F     = (const float*)d_in[0];
    const float* imgs  = (const float*)d_in[1];
    const float* masks = (const float*)d_in[2];
    const float* gw1 = (const float*)d_in[3];  const float* gb1 = (const float*)d_in[4];
    const float* gw2 = (const float*)d_in[5];  const float* gb2 = (const float*)d_in[6];
    const float* gw3 = (const float*)d_in[7];  const float* gb3 = (const float*)d_in[8];
    const float* gw4 = (const float*)d_in[9];  const float* gb4 = (const float*)d_in[10];
    const float* gw5 = (const float*)d_in[11]; const float* gb5 = (const float*)d_in[12];
    const float* cw  = (const float*)d_in[13]; const float* cb  = (const float*)d_in[14];
    float* out = (float*)d_out;

    // ---- workspace layout (float offsets), ~150 MB ----
    float* W = (float*)d_ws;
    ushort_t* Xcl2h = (ushort_t*)(W);                 // [8][260][260][32] fp16 h
    ushort_t* Xcl4h = (ushort_t*)(W);                 // [8][130][130][128] fp16 h
    float*    Opart = W;                              // [4][8][128][4096] f32
    float*    lpart = W + 16777216;                   // [4][8][4096]
    ushort_t* Xcl3h = (ushort_t*)(W + 17305600);      // [8][132][132][64] fp16 h
    ushort_t* Vf    = (ushort_t*)(W + 17305600);      // [8][128][8][64][8] bf16 V-frags
    float*    s4   = W + 26226688;                    // [8][256][64][64] f32
    ushort_t* Fa   = (ushort_t*)(W + 26226688);       // [8][128][8][64][8] bf16 K-frags (aliases s4)
    ushort_t* Ft16 = (ushort_t*)(W + 30420992);       // [8][4096][128] bf16
    ushort_t* W2h = (ushort_t*)(W + 34615296);
    ushort_t* W2l = (ushort_t*)(W + 34640896);
    ushort_t* W3h = (ushort_t*)(W + 34666496);
    ushort_t* W3l = (ushort_t*)(W + 34768896);
    ushort_t* W4h = (ushort_t*)(W + 34871296);
    ushort_t* W4l = (ushort_t*)(W + 35018752);
    float* gate = W + 35166208;
    float* invn = W + 35198976;
    ushort_t* Xinh = (ushort_t*)(W + 35231744);       // [8][262][262][4] fp16 h + slack
    ushort_t* W1h  = (ushort_t*)(W + 37428416);       // [7][32][32] fp16
    ushort_t* W1l  = (ushort_t*)(W + 37432000);
    float* cwT = W + 37436416;                        // [128][256] f32 (131 KB)

    // ---- weight transforms + conv1 input prep ----
    transform_w_k<<<dim3(200),  256, 0, stream>>>(gw2, W2h, W2l, 64, 32, 25);
    transform_w_k<<<dim3(800),  256, 0, stream>>>(gw3, W3h, W3l, 128, 64, 25);
    transform_w_k<<<dim3(1152), 256, 0, stream>>>(gw4, W4h, W4l, 256, 128, 9);
    transform_w1_k<<<dim3(28), 256, 0, stream>>>(gw1, W1h, W1l);
    transform_cw_k<<<dim3(64), 256, 0, stream>>>(cw, cwT);
    prep_in_k<<<dim3(262, 8), 256, 0, stream>>>(imgs, masks, Xinh);

    // ---- conv stack (2-term split: weights h+l, activations h only) ----
    conv1_mfma_k<<<dim3(4, 256, 8), 256, 0, stream>>>(Xinh, W1h, W1l, gb1, Xcl2h);
    pad_cl_k<<<dim3(260, 8), 256, 0, stream>>>(Xcl2h, 260, 260, 2, 32, 256, 256);
    conv_mfma_k<5, 2, 32, 32, 64, 128, true><<<dim3(1, 128, 8), 256, 0, stream>>>(
        Xcl2h, W2h, W2l, gb2, 260, 260, 64, Xcl3h, 132, 132, 2, nullptr);
    pad_cl_k<<<dim3(132, 8), 256, 0, stream>>>(Xcl3h, 132, 132, 2, 64, 128, 128);
    conv3_mfma_k<<<dim3(1, 32, 16), 256, 0, stream>>>(Xcl3h, W3h, W3l, gb3, Xcl4h);
    pad_cl_k<<<dim3(130, 8), 256, 0, stream>>>(Xcl4h, 130, 130, 1, 128, 128, 128);
    conv_mfma_k<3, 2, 128, 32, 128, 64, false><<<dim3(1, 64, 16), 256, 0, stream>>>(
        Xcl4h, W4h, W4l, gb4, 130, 130, 256, nullptr, 0, 0, 0, s4);
    conv5_gate_k<<<dim3(64, 8), 256, 0, stream>>>(s4, gw5, gb5, gate);

    // ---- attention ----
    invn_k<<<dim3(16, 8), 256, 0, stream>>>(F, invn);
    prep_bf16_k<<<dim3(64, 8), 256, 0, stream>>>(F, Vf, Fa, Ft16);
    flash_attn_k<<<dim3(8, 256, 1), 64, 0, stream>>>(Ft16, Vf, Fa, invn, gate, Opart, lpart);
    combiner_k<<<dim3(16, 8), 256, 0, stream>>>(Opart, lpart, F, cwT, cb, out);
}

// Round 14
// 538.783 us; speedup vs baseline: 1.2494x; 1.2494x over previous
//
#include <hip/hip_runtime.h>
#include <hip/hip_bf16.h>
#include <hip/hip_fp16.h>
#include <math.h>

// GatedAttention R29: combiner OTILE=32 fix. R28 post-mortem: acc[128] spilled
// (VGPR=76 < 128 needed; VALUBusy 8%) AND grid (16,8)=128 blocks starved half
// the chip (occ 5.7%) -> 186us. The "read-once" goal was misguided: Opart (67MB)
// is L3-hot (FETCH=42MB). Fix: acc[32]/thread (no spill), grid (16,8,4)=512
// blocks (2/CU, 8 waves/CU), Opart re-read 4x from L3 (vs 8x in R15 version),
// cwT contiguous scalar weight path kept. Flash/conv = R26/R28 (R26 flash:
// q=64 1-wave reg-dbuf frag-ordered; conv3 OYB=4).

#define PI_F 3.1415926f

typedef __attribute__((ext_vector_type(8))) short short8;
typedef __attribute__((ext_vector_type(4))) float f32x4;
typedef _Float16 half8 __attribute__((ext_vector_type(8)));
typedef __attribute__((ext_vector_type(4))) unsigned short u16x4;
typedef unsigned short ushort_t;

__device__ __forceinline__ ushort_t f2bf(float x) {
    unsigned u = __float_as_uint(x);
    unsigned r = (u + 0x7FFFu + ((u >> 16) & 1u)) >> 16;
    return (ushort_t)r;
}
__device__ __forceinline__ void split16(float x, ushort_t& h, ushort_t& l) {
    __half hh = __float2half(x);
    h = __half_as_ushort(hh);
    l = __half_as_ushort(__float2half(x - __half2float(hh)));
}
__device__ __forceinline__ ushort_t f2h(float x) {
    return __half_as_ushort(__float2half(x));
}
__device__ __forceinline__ int swz(int r, int c) {
    return ((c ^ r ^ (r >> 2)) & 3) << 3;
}

// ---------------- weight transform: OIHW fp32 -> [ky*kx][oc][ic] fp16 hi/lo --------
__global__ __launch_bounds__(256) void transform_w_k(
    const float* __restrict__ w, ushort_t* __restrict__ Wh, ushort_t* __restrict__ Wl,
    int Cout, int Cin, int KK)
{
    int idx = blockIdx.x * 256 + threadIdx.x;
    int N = Cout * Cin * KK;
    if (idx >= N) return;
    int oc = idx / (Cin * KK);
    int rem = idx - oc * (Cin * KK);
    int ic = rem / KK;
    int t = rem - ic * KK;
    float v = w[idx];
    long dst = ((long)t * Cout + oc) * Cin + ic;
    split16(v, Wh[dst], Wl[dst]);
}

// ------- conv1 weight transform: [32][4][7][7] -> [7 ky][32 oc][32 k=kx*4+ic] ------
__global__ __launch_bounds__(256) void transform_w1_k(
    const float* __restrict__ w, ushort_t* __restrict__ Wh, ushort_t* __restrict__ Wl)
{
    int idx = blockIdx.x * 256 + threadIdx.x;
    if (idx >= 7 * 32 * 32) return;
    int ky = idx / 1024;
    int rem = idx - ky * 1024;
    int oc = rem >> 5;
    int k = rem & 31;
    float v = 0.f;
    if (k < 28) {
        int kx = k >> 2, ic = k & 3;
        v = w[((oc * 4 + ic) * 7 + ky) * 7 + kx];
    }
    split16(v, Wh[idx], Wl[idx]);
}

// ------- combiner weight transform: cw[o][256] -> cwT[c][ a:o | f:128+o ] ---------
__global__ __launch_bounds__(256) void transform_cw_k(
    const float* __restrict__ cw, float* __restrict__ cwT)
{
    int idx = blockIdx.x * 256 + threadIdx.x;
    if (idx >= 16384) return;
    int o = idx >> 7, c = idx & 127;
    cwT[c * 256 + o]       = cw[o * 256 + c];
    cwT[c * 256 + 128 + o] = cw[o * 256 + 128 + c];
}

// ------- prep conv1 input: reflect-pad(3) -> channel-last [8][262][262][4] fp16 h --
__global__ __launch_bounds__(256) void prep_in_k(
    const float* __restrict__ imgs, const float* __restrict__ masks,
    ushort_t* __restrict__ Xh)
{
    const int iy = blockIdx.x, b = blockIdx.y;
    int sy = iy - 3; if (sy < 0) sy = -sy; if (sy >= 256) sy = 510 - sy;
    const int rb = sy << 8;
    const float* i0 = imgs + (long)b * 3 * 65536;
    const float* mk = masks + (long)b * 65536;
    for (int x = threadIdx.x; x < 262; x += 256) {
        int sx = x - 3; if (sx < 0) sx = -sx; if (sx >= 256) sx = 510 - sx;
        u16x4 hv;
        hv[0] = f2h(i0[rb + sx]);
        hv[1] = f2h(i0[65536 + rb + sx]);
        hv[2] = f2h(i0[131072 + rb + sx]);
        hv[3] = f2h(mk[rb + sx]);
        long o = ((long)(b * 262 + iy) * 262 + x) * 4;
        *(u16x4*)&Xh[o] = hv;
    }
}

// ------- conv1 MFMA (2-term): 32 oc x 64 px per block -----------
__global__ __launch_bounds__(256) void conv1_mfma_k(
    const ushort_t* __restrict__ Xinh,
    const ushort_t* __restrict__ W1h, const ushort_t* __restrict__ W1l,
    const float* __restrict__ bias, ushort_t* __restrict__ Oh)
{
    const int tid = threadIdx.x, lane = tid & 63, wid = tid >> 6;
    const int wm = wid & 1, wn = wid >> 1, l15 = lane & 15, quad = lane >> 4;
    const int ox0 = blockIdx.x * 64;
    const int oy = blockIdx.y, b = blockIdx.z;
    f32x4 acc[2];
    acc[0] = (f32x4){0.f, 0.f, 0.f, 0.f};
    acc[1] = (f32x4){0.f, 0.f, 0.f, 0.f};
#pragma unroll
    for (int ky = 0; ky < 7; ++ky) {
        long wo = (long)(ky * 32 + wm * 16 + l15) * 32 + quad * 8;
        half8 Ah = *(const half8*)&W1h[wo];
        half8 Al = *(const half8*)&W1l[wo];
        long xrow = ((long)(b * 262 + oy + ky) * 262 + ox0) * 4;
#pragma unroll
        for (int ni = 0; ni < 2; ++ni) {
            long xo = xrow + (wn * 32 + ni * 16 + l15) * 4 + quad * 8;
            half8 Bh = *(const half8*)&Xinh[xo];
            acc[ni] = __builtin_amdgcn_mfma_f32_16x16x32_f16(Ah, Bh, acc[ni], 0, 0, 0);
            acc[ni] = __builtin_amdgcn_mfma_f32_16x16x32_f16(Al, Bh, acc[ni], 0, 0, 0);
        }
    }
    const int ocf = wm * 16 + quad * 4;
    float4 bv = *(const float4*)&bias[ocf];
#pragma unroll
    for (int ni = 0; ni < 2; ++ni) {
        int n = ox0 + wn * 32 + ni * 16 + l15;
        u16x4 hv;
        hv[0] = f2h(fmaxf(acc[ni][0] + bv.x, 0.f));
        hv[1] = f2h(fmaxf(acc[ni][1] + bv.y, 0.f));
        hv[2] = f2h(fmaxf(acc[ni][2] + bv.z, 0.f));
        hv[3] = f2h(fmaxf(acc[ni][3] + bv.w, 0.f));
        long o = ((long)(b * 260 + oy + 2) * 260 + n + 2) * 32 + ocf;
        *(u16x4*)&Oh[o] = hv;
    }
}

// ------- pad-fill for channel-last reflect-padded h-only buffers ----
__global__ __launch_bounds__(256) void pad_cl_k(
    ushort_t* __restrict__ Xh, int Hp, int Wp, int PAD, int C, int H, int W)
{
    const int iy = blockIdx.x, b = blockIdx.y;
    int t = iy - PAD; if (t < 0) t = -t; if (t >= H) t = 2 * H - 2 - t;
    const int iys = t + PAD;
    const long rowd = ((long)(b * Hp + iy) * Wp) * C;
    const long rows = ((long)(b * Hp + iys) * Wp) * C;
    const int nch = Wp * (C >> 3);
    for (int idx = threadIdx.x; idx < nch; idx += 256) {
        int x = idx / (C >> 3);
        int cg = (idx - x * (C >> 3)) << 3;
        int t2 = x - PAD; if (t2 < 0) t2 = -t2; if (t2 >= W) t2 = 2 * W - 2 - t2;
        int xs = t2 + PAD;
        if (xs == x && iys == iy) continue;
        *(int4*)&Xh[rowd + (long)x * C + cg] = *(const int4*)&Xh[rows + (long)xs * C + cg];
    }
}

// ------- MFMA conv (2-term split), swizzled LDS, de-interleave for S=2 ----
template<int K, int S, int CIN, int CSTG, int MT, int NPX, bool WRITE_CL>
__global__ __launch_bounds__(256, 2) void conv_mfma_k(
    const ushort_t* __restrict__ Xh,
    const ushort_t* __restrict__ Wh, const ushort_t* __restrict__ Wl,
    const float* __restrict__ bias,
    int Hp, int Wp, int CoutT,
    ushort_t* __restrict__ Oh, int Hpn, int Wpn, int NP,
    float* __restrict__ Ofp)
{
    constexpr int WS = (NPX - 1) * S + K;
    constexpr int WS2 = (WS + 1) / 2;
    constexpr int MF = MT / 32;
    constexpr int NF = NPX / 32;
    __shared__ ushort_t Bsh[WS * CSTG];
    __shared__ ushort_t Ash[K * MT * CSTG];
    __shared__ ushort_t Asl[K * MT * CSTG];
    const int tid = threadIdx.x, lane = tid & 63, wid = tid >> 6;
    const int wm = wid & 1, wn = wid >> 1, l15 = lane & 15, quad = lane >> 4;
    const int bx = blockIdx.x, oy = blockIdx.y;
    const int NOC = CoutT / MT;
    const int ocg = blockIdx.z % NOC, b = blockIdx.z / NOC;
    const int ox0 = bx * NPX;

    f32x4 acc[MF][NF];
#pragma unroll
    for (int mi = 0; mi < MF; ++mi)
#pragma unroll
        for (int ni = 0; ni < NF; ++ni) acc[mi][ni] = (f32x4){0.f, 0.f, 0.f, 0.f};

#pragma unroll
    for (int ky = 0; ky < K; ++ky) {
        const long rowoff = ((long)(b * Hp + oy * S + ky) * Wp + ox0 * S) * CIN;
        for (int cs = 0; cs < CIN; cs += CSTG) {
            __syncthreads();
            constexpr int NCH = WS * CSTG / 8;
#pragma unroll
            for (int it = 0; it < (NCH + 255) / 256; ++it) {
                int flat = tid + it * 256;
                if (flat < NCH) {
                    int e0 = flat * 8;
                    int x = e0 / CSTG;
                    int cpos = (e0 - x * CSTG) >> 3;
                    int xs = (S == 1) ? x : ((x >> 1) + (x & 1) * WS2);
                    *(int4*)&Bsh[xs * CSTG + swz(xs, cpos)] =
                        *(const int4*)&Xh[rowoff + (long)x * CIN + cs + cpos * 8];
                }
            }
            constexpr int NW = K * MT * CSTG / 8;
#pragma unroll
            for (int it = 0; it < (NW + 255) / 256; ++it) {
                int flat = tid + it * 256;
                if (flat < NW) {
                    int e0 = flat * 8;
                    int kx = e0 / (MT * CSTG);
                    int rem = e0 - kx * MT * CSTG;
                    int oc = rem / CSTG;
                    int cpos = (rem - oc * CSTG) >> 3;
                    int arow = kx * MT + oc;
                    int dst = arow * CSTG + swz(arow, cpos);
                    long src = ((long)((ky * K + kx) * CoutT + ocg * MT + oc)) * CIN + cs + cpos * 8;
                    *(int4*)&Ash[dst] = *(const int4*)&Wh[src];
                    *(int4*)&Asl[dst] = *(const int4*)&Wl[src];
                }
            }
            __syncthreads();
#pragma unroll
            for (int kx = 0; kx < K; ++kx) {
                half8 Ah[MF], Al[MF], Bh[NF];
#pragma unroll
                for (int mi = 0; mi < MF; ++mi) {
                    int arow = kx * MT + wm * (MT / 2) + mi * 16 + l15;
                    int ao = arow * CSTG + swz(arow, quad);
                    Ah[mi] = *(const half8*)&Ash[ao];
                    Al[mi] = *(const half8*)&Asl[ao];
                }
#pragma unroll
                for (int ni = 0; ni < NF; ++ni) {
                    int m = wn * (NPX / 2) + ni * 16 + l15;
                    int xs = (S == 1) ? (m + kx) : (m + (kx >> 1) + (kx & 1) * WS2);
                    Bh[ni] = *(const half8*)&Bsh[xs * CSTG + swz(xs, quad)];
                }
#pragma unroll
                for (int mi = 0; mi < MF; ++mi)
#pragma unroll
                    for (int ni = 0; ni < NF; ++ni) {
                        acc[mi][ni] = __builtin_amdgcn_mfma_f32_16x16x32_f16(Ah[mi], Bh[ni], acc[mi][ni], 0, 0, 0);
                        acc[mi][ni] = __builtin_amdgcn_mfma_f32_16x16x32_f16(Al[mi], Bh[ni], acc[mi][ni], 0, 0, 0);
                    }
            }
        }
    }
#pragma unroll
    for (int ni = 0; ni < NF; ++ni) {
        const int n = ox0 + wn * (NPX / 2) + ni * 16 + l15;
#pragma unroll
        for (int mi = 0; mi < MF; ++mi) {
            const int ocf = ocg * MT + wm * (MT / 2) + mi * 16 + quad * 4;
            float4 bv = *(const float4*)&bias[ocf];
            float v0 = fmaxf(acc[mi][ni][0] + bv.x, 0.f);
            float v1 = fmaxf(acc[mi][ni][1] + bv.y, 0.f);
            float v2 = fmaxf(acc[mi][ni][2] + bv.z, 0.f);
            float v3 = fmaxf(acc[mi][ni][3] + bv.w, 0.f);
            if (WRITE_CL) {
                long o = ((long)(b * Hpn + oy + NP) * Wpn + n + NP) * CoutT + ocf;
                u16x4 hv;
                hv[0] = f2h(v0); hv[1] = f2h(v1); hv[2] = f2h(v2); hv[3] = f2h(v3);
                *(u16x4*)&Oh[o] = hv;
            } else {
                long o = ((long)(b * CoutT + ocf) << 12) + (oy << 6) + n;
                Ofp[o] = v0;
                Ofp[o + 4096] = v1;
                Ofp[o + 8192] = v2;
                Ofp[o + 12288] = v3;
            }
        }
    }
}

// ------- conv3 dedicated: K5 S1 CIN64 CSTG32 MT64 NPX128, OYB=4 rows/block ----
__global__ __launch_bounds__(256, 2) void conv3_mfma_k(
    const ushort_t* __restrict__ Xh,
    const ushort_t* __restrict__ Wh, const ushort_t* __restrict__ Wl,
    const float* __restrict__ bias, ushort_t* __restrict__ Oh)
{
    __shared__ ushort_t Bsh[4][132 * 32];   // 33792 B
    __shared__ ushort_t Ash[5 * 64 * 32];   // 20480 B
    __shared__ ushort_t Asl[5 * 64 * 32];   // 20480 B
    const int tid = threadIdx.x, lane = tid & 63, wid = tid >> 6;
    const int wm = wid & 1, wn = wid >> 1, l15 = lane & 15, quad = lane >> 4;
    const int oy0 = blockIdx.y * 4;
    const int ocg = blockIdx.z & 1, b = blockIdx.z >> 1;

    f32x4 acc[4][2][4];
#pragma unroll
    for (int oyi = 0; oyi < 4; ++oyi)
#pragma unroll
        for (int mi = 0; mi < 2; ++mi)
#pragma unroll
            for (int ni = 0; ni < 4; ++ni) acc[oyi][mi][ni] = (f32x4){0.f, 0.f, 0.f, 0.f};

    for (int csi = 0; csi < 2; ++csi) {
        const int cb = csi * 32;
        for (int flat = tid; flat < 3 * 528; flat += 256) {
            int r0 = flat / 528;
            int rem = flat - r0 * 528;
            int e0 = rem * 8;
            int x = e0 >> 5;
            int cpos = (e0 & 31) >> 3;
            *(int4*)&Bsh[r0][x * 32 + swz(x, cpos)] =
                *(const int4*)&Xh[((long)(b * 132 + oy0 + r0) * 132 + x) * 64 + cb + cpos * 8];
        }
        for (int ky = 0; ky < 5; ++ky) {
            {
                const int row = oy0 + ky + 3;
                const int slot = (ky + 3) & 3;
                for (int flat = tid; flat < 528; flat += 256) {
                    int e0 = flat * 8;
                    int x = e0 >> 5;
                    int cpos = (e0 & 31) >> 3;
                    *(int4*)&Bsh[slot][x * 32 + swz(x, cpos)] =
                        *(const int4*)&Xh[((long)(b * 132 + row) * 132 + x) * 64 + cb + cpos * 8];
                }
            }
            for (int flat = tid; flat < 1280; flat += 256) {
                int e0 = flat * 8;
                int kx = e0 >> 11;
                int rem = e0 & 2047;
                int oc = rem >> 5;
                int cpos = (rem & 31) >> 3;
                int arow = kx * 64 + oc;
                int dst = arow * 32 + swz(arow, cpos);
                long src = ((long)((ky * 5 + kx) * 128 + ocg * 64 + oc)) * 64 + cb + cpos * 8;
                *(int4*)&Ash[dst] = *(const int4*)&Wh[src];
                *(int4*)&Asl[dst] = *(const int4*)&Wl[src];
            }
            __syncthreads();
#pragma unroll
            for (int kx = 0; kx < 5; ++kx) {
                half8 Ah[2], Al[2];
#pragma unroll
                for (int mi = 0; mi < 2; ++mi) {
                    int arow = kx * 64 + wm * 32 + mi * 16 + l15;
                    int ao = arow * 32 + swz(arow, quad);
                    Ah[mi] = *(const half8*)&Ash[ao];
                    Al[mi] = *(const half8*)&Asl[ao];
                }
#pragma unroll
                for (int oyi = 0; oyi < 4; ++oyi) {
                    const int slot = (ky + oyi) & 3;
                    half8 Bh[4];
#pragma unroll
                    for (int ni = 0; ni < 4; ++ni) {
                        int xs = wn * 64 + ni * 16 + l15 + kx;
                        Bh[ni] = *(const half8*)&Bsh[slot][xs * 32 + swz(xs, quad)];
                    }
#pragma unroll
                    for (int mi = 0; mi < 2; ++mi)
#pragma unroll
                        for (int ni = 0; ni < 4; ++ni) {
                            acc[oyi][mi][ni] = __builtin_amdgcn_mfma_f32_16x16x32_f16(Ah[mi], Bh[ni], acc[oyi][mi][ni], 0, 0, 0);
                            acc[oyi][mi][ni] = __builtin_amdgcn_mfma_f32_16x16x32_f16(Al[mi], Bh[ni], acc[oyi][mi][ni], 0, 0, 0);
                        }
                }
            }
            __syncthreads();
        }
    }
    const int ocf = ocg * 64 + wm * 32 + quad * 4;
#pragma unroll
    for (int oyi = 0; oyi < 4; ++oyi) {
        const int oy = oy0 + oyi;
#pragma unroll
        for (int ni = 0; ni < 4; ++ni) {
            const int n = wn * 64 + ni * 16 + l15;
#pragma unroll
            for (int mi = 0; mi < 2; ++mi) {
                const int oc4 = ocf + mi * 16;
                float4 bv = *(const float4*)&bias[oc4];
                u16x4 hv;
                hv[0] = f2h(fmaxf(acc[oyi][mi][ni][0] + bv.x, 0.f));
                hv[1] = f2h(fmaxf(acc[oyi][mi][ni][1] + bv.y, 0.f));
                hv[2] = f2h(fmaxf(acc[oyi][mi][ni][2] + bv.z, 0.f));
                hv[3] = f2h(fmaxf(acc[oyi][mi][ni][3] + bv.w, 0.f));
                long o = ((long)(b * 130 + oy + 1) * 130 + n + 1) * 128 + oc4;
                *(u16x4*)&Oh[o] = hv;
            }
        }
    }
}

// -------- conv5 (256->1, K3 S1 P1) + relu + gate ----------
__global__ __launch_bounds__(256) void conv5_gate_k(
    const float* __restrict__ s4, const float* __restrict__ w,
    const float* __restrict__ bias, float* __restrict__ gate)
{
    const int tid = threadIdx.x;
    const int lane = tid & 63, g = tid >> 6;
    const int oy = blockIdx.x, b = blockIdx.y;
    int ixo[3], iyo[3];
#pragma unroll
    for (int k = 0; k < 3; ++k) {
        int ix = lane + k - 1; if (ix < 0) ix = -ix; if (ix >= 64) ix = 126 - ix;
        int iy = oy + k - 1; if (iy < 0) iy = -iy; if (iy >= 64) iy = 126 - iy;
        ixo[k] = ix; iyo[k] = iy << 6;
    }
    float part = 0.f;
    const float* inb = s4 + ((long)b * 256 + g * 64) * 4096;
    const float* wg = w + g * 64 * 9;
    for (int ic = 0; ic < 64; ++ic) {
        const float* inc = inb + ic * 4096;
        const float* wc = wg + ic * 9;
#pragma unroll
        for (int ky = 0; ky < 3; ++ky)
#pragma unroll
            for (int kx = 0; kx < 3; ++kx)
                part = fmaf(wc[ky * 3 + kx], inc[iyo[ky] + ixo[kx]], part);
    }
    __shared__ float red[4][64];
    red[g][lane] = part;
    __syncthreads();
    if (tid < 64) {
        float s = bias[0] + red[0][tid] + red[1][tid] + red[2][tid] + red[3][tid];
        s = fmaxf(s, 0.f);
        gate[(b << 12) + (oy << 6) + tid] = tanf(PI_F * (tanhf(s) - 0.5f));
    }
}

// ---------------- invn[b][p] = 1/sqrt(sum_c (F+1e-7)^2) ----------------
__global__ __launch_bounds__(256) void invn_k(const float* __restrict__ F, float* __restrict__ invn)
{
    const int p = blockIdx.x * 256 + threadIdx.x;
    const int b = blockIdx.y;
    const float* Fb = F + (long)b * 524288;
    float ss = 0.f;
#pragma unroll 8
    for (int c = 0; c < 128; ++c) {
        float v = Fb[c * 4096 + p] + 1e-7f;
        ss = fmaf(v, v, ss);
    }
    invn[(b << 12) + p] = 1.0f / sqrtf(ss);
}

// -------- prep: Ft16[b][p][c] (for Bq), Vf[b][chunk][ct][lane][8] (PV A-frags),
//          Fa[b][chunk][sub*4+cs][lane][8] (QK A-frags, permuted rows baked in). ---
__global__ __launch_bounds__(256) void prep_bf16_k(
    const float* __restrict__ F, ushort_t* __restrict__ Vf,
    ushort_t* __restrict__ Fa, ushort_t* __restrict__ Ft16)
{
    __shared__ float Ls[128][65];
    const int tid = threadIdx.x;
    const int lane = tid & 63, wv = tid >> 6;
    const int p0 = blockIdx.x * 64, b = blockIdx.y;
#pragma unroll 8
    for (int cc = 0; cc < 32; ++cc) {
        int c = wv * 32 + cc;
        long idx = ((long)b * 128 + c) * 4096 + p0 + lane;
        Ls[c][lane] = F[idx];
    }
    __syncthreads();
    // Ft16 (p-major) for Bq
#pragma unroll 8
    for (int i = 0; i < 32; ++i) {
        int flat = tid + 256 * i;
        int c = flat & 127, pl_ = flat >> 7;
        Ft16[((long)b * 4096 + p0 + pl_) * 128 + c] = f2bf(Ls[c][pl_]);
    }
    const int chunk0 = blockIdx.x * 2;
    // Vf: frag (ct, lane=(quad<<4)|l15) elem e -> F[b][ct*16+l15][chunk*32+quad*8+e]
#pragma unroll
    for (int s = tid; s < 1024; s += 256) {
        int ck = s >> 9, rem = s & 511;
        int ct = rem >> 6, ln = rem & 63;
        int c = ct * 16 + (ln & 15);
        int pl = ck * 32 + (ln >> 4) * 8;
        ushort_t tmp[8];
#pragma unroll
        for (int e = 0; e < 8; ++e) tmp[e] = f2bf(Ls[c][pl + e]);
        *(short8*)&Vf[(((long)(b * 128 + chunk0 + ck) * 8 + ct) * 64 + ln) * 8] = *(short8*)tmp;
    }
    // Fa: frag (f=sub*4+cs, lane) elem e ->
    //   F[b][(f&3)*32+(ln>>4)*8+e][chunk*32 + ((l15&12)<<1)+(l15&3) + (f>>2)*4]
#pragma unroll
    for (int s = tid; s < 1024; s += 256) {
        int ck = s >> 9, rem = s & 511;
        int f = rem >> 6, ln = rem & 63;
        int l15_ = ln & 15;
        int c0 = (f & 3) * 32 + (ln >> 4) * 8;
        int pl = ck * 32 + ((l15_ & 12) << 1) + (l15_ & 3) + (f >> 2) * 4;
        ushort_t tmp[8];
#pragma unroll
        for (int e = 0; e < 8; ++e) tmp[e] = f2bf(Ls[c0 + e][pl]);
        *(short8*)&Fa[(((long)(b * 128 + chunk0 + ck) * 8 + f) * 64 + ln) * 8] = *(short8*)tmp;
    }
}

// -------- flash attention (R26): q=64, 1 wave, reg-dbuf, fragment-ordered loads ---
__global__ __launch_bounds__(64, 1) void flash_attn_k(
    const ushort_t* __restrict__ Ft16, const ushort_t* __restrict__ Vf,
    const ushort_t* __restrict__ Fa,
    const float* __restrict__ invn, const float* __restrict__ gate,
    float* __restrict__ Opart, float* __restrict__ lpart)
{
    const int lane = threadIdx.x & 63;
    const int l15 = lane & 15, quad = lane >> 4;
    const int b = blockIdx.x;
    const int qb = blockIdx.y & 63, ks = blockIdx.y >> 6;
    const int q0 = qb * 64;
    const int bp = b << 12;
    const ushort_t* Ftb = Ft16 + (long)b * 4096 * 128;
    const ushort_t* FaB = Fa + (long)b * 128 * 8 * 512;
    const ushort_t* VfB = Vf + (long)b * 128 * 8 * 512;

    short8 Bq[4][4];
#pragma unroll
    for (int ni = 0; ni < 4; ++ni)
#pragma unroll
        for (int cs = 0; cs < 4; ++cs)
            Bq[ni][cs] = *(const short8*)&Ftb[(long)(q0 + ni * 16 + l15) * 128 + cs * 32 + quad * 8];

    f32x4 O[8][4];
#pragma unroll
    for (int ct = 0; ct < 8; ++ct)
#pragma unroll
        for (int ni = 0; ni < 4; ++ni) O[ct][ni] = (f32x4){0.f, 0.f, 0.f, 0.f};
    float l_acc[4] = {0.f, 0.f, 0.f, 0.f};

    union BeU { short8 v; __hip_bfloat162 h[4]; };
    const int p_beg = ks * 1024;
    const int ck_beg = ks * 32;
    const long lane8 = (long)lane * 8;

    short8 Ap[2][2][4];
    short8 Va[2][8];
    float4 ivb[2][2], gtb[2][2];

    {
        const long fb = (long)(ck_beg) * 4096;
#pragma unroll
        for (int sub = 0; sub < 2; ++sub) {
#pragma unroll
            for (int cs = 0; cs < 4; ++cs)
                Ap[0][sub][cs] = *(const short8*)&FaB[fb + (long)(sub * 4 + cs) * 512 + lane8];
            ivb[0][sub] = *(const float4*)&invn[bp + p_beg + quad * 8 + sub * 4];
            gtb[0][sub] = *(const float4*)&gate[bp + p_beg + quad * 8 + sub * 4];
        }
#pragma unroll
        for (int ct = 0; ct < 8; ++ct)
            Va[0][ct] = *(const short8*)&VfB[fb + (long)ct * 512 + lane8];
    }

#pragma unroll 2
    for (int t = 0; t < 32; ++t) {
        const int cur = t & 1, nxt = cur ^ 1;
        if (t + 1 < 32) {
            const int p1 = p_beg + (t + 1) * 32;
            const long fb = (long)(ck_beg + t + 1) * 4096;
#pragma unroll
            for (int sub = 0; sub < 2; ++sub) {
#pragma unroll
                for (int cs = 0; cs < 4; ++cs)
                    Ap[nxt][sub][cs] = *(const short8*)&FaB[fb + (long)(sub * 4 + cs) * 512 + lane8];
                ivb[nxt][sub] = *(const float4*)&invn[bp + p1 + quad * 8 + sub * 4];
                gtb[nxt][sub] = *(const float4*)&gate[bp + p1 + quad * 8 + sub * 4];
            }
#pragma unroll
            for (int ct = 0; ct < 8; ++ct)
                Va[nxt][ct] = *(const short8*)&VfB[fb + (long)ct * 512 + lane8];
        }
        BeU be[4];
#pragma unroll
        for (int sub = 0; sub < 2; ++sub) {
            f32x4 Sa[4];
#pragma unroll
            for (int ni = 0; ni < 4; ++ni) Sa[ni] = (f32x4){0.f, 0.f, 0.f, 0.f};
#pragma unroll
            for (int cs = 0; cs < 4; ++cs)
#pragma unroll
                for (int ni = 0; ni < 4; ++ni)
                    Sa[ni] = __builtin_amdgcn_mfma_f32_16x16x32_bf16(Ap[cur][sub][cs], Bq[ni][cs], Sa[ni], 0, 0, 0);
            const float4 iv = ivb[cur][sub];
            const float4 gt = gtb[cur][sub];
#pragma unroll
            for (int ni = 0; ni < 4; ++ni) {
                float e0 = __expf(fmaf(Sa[ni][0], iv.x, gt.x));
                float e1 = __expf(fmaf(Sa[ni][1], iv.y, gt.y));
                float e2 = __expf(fmaf(Sa[ni][2], iv.z, gt.z));
                float e3 = __expf(fmaf(Sa[ni][3], iv.w, gt.w));
                be[ni].h[sub * 2]     = __float22bfloat162_rn(make_float2(e0, e1));
                be[ni].h[sub * 2 + 1] = __float22bfloat162_rn(make_float2(e2, e3));
                l_acc[ni] += (e0 + e1) + (e2 + e3);
            }
        }
#pragma unroll
        for (int ct = 0; ct < 8; ++ct)
#pragma unroll
            for (int ni = 0; ni < 4; ++ni)
                O[ct][ni] = __builtin_amdgcn_mfma_f32_16x16x32_bf16(Va[cur][ct], be[ni].v, O[ct][ni], 0, 0, 0);
    }

#pragma unroll
    for (int ni = 0; ni < 4; ++ni) {
        float lt = l_acc[ni];
        lt += __shfl_xor(lt, 16);
        lt += __shfl_xor(lt, 32);
        if (quad == 0)
            lpart[(ks * 8 + b) * 4096 + q0 + ni * 16 + l15] = lt;
    }
    float* Ob = Opart + (long)(ks * 8 + b) * 524288;
#pragma unroll
    for (int ct = 0; ct < 8; ++ct)
#pragma unroll
        for (int ni = 0; ni < 4; ++ni) {
            int c = ct * 16 + quad * 4;
            int q = q0 + ni * 16 + l15;
#pragma unroll
            for (int r = 0; r < 4; ++r)
                Ob[((long)(c + r) << 12) + q] = O[ct][ni][r];
        }
}

// ---------------- combiner (R29): OTILE=32, grid (16,8,4). acc[32] spill-free;
// cwT contiguous weight path; Opart/F L3-resident (4x re-read is cheap). ----------
__global__ __launch_bounds__(256) void combiner_k(
    const float* __restrict__ Opart, const float* __restrict__ lpart,
    const float* __restrict__ F, const float* __restrict__ cwT,
    const float* __restrict__ cb, float* __restrict__ out)
{
    const int tid = threadIdx.x;
    const int q = blockIdx.x * 256 + tid;
    const int b = blockIdx.y;
    const int o0 = blockIdx.z << 5;
    float lsum = 0.f;
#pragma unroll
    for (int ks = 0; ks < 4; ++ks) lsum += lpart[(ks * 8 + b) * 4096 + q];
    float il = 1.0f / lsum;
    const float* Fb = F + (long)b * 524288 + q;
    float acc[32];
#pragma unroll
    for (int j = 0; j < 32; ++j) acc[j] = cb[o0 + j];
    for (int c = 0; c < 128; ++c) {
        float a = 0.f;
#pragma unroll
        for (int ks = 0; ks < 4; ++ks)
            a += Opart[(long)(ks * 8 + b) * 524288 + (long)c * 4096 + q];
        a *= il;
        float f = Fb[(long)c * 4096];
        const float* wc = cwT + c * 256 + o0;
#pragma unroll
        for (int j = 0; j < 32; ++j)
            acc[j] = fmaf(wc[j], a, fmaf(wc[128 + j], f, acc[j]));
    }
#pragma unroll
    for (int j = 0; j < 32; ++j)
        out[((long)(b * 128 + o0 + j) << 12) + q] = acc[j];
}

// =====================================================================================
extern "C" void kernel_launch(void* const* d_in, const int* in_sizes, int n_in,
                              void* d_out, int out_size, void* d_ws, size_t ws_size,
                              hipStream_t stream)
{
    const float* F     = (const float*)d_in[0];
    const float* imgs  = (const float*)d_in[1];
    const float* masks = (const float*)d_in[2];
    const float* gw1 = (const float*)d_in[3];  const float* gb1 = (const float*)d_in[4];
    const float* gw2 = (const float*)d_in[5];  const float* gb2 = (const float*)d_in[6];
    const float* gw3 = (const float*)d_in[7];  const float* gb3 = (const float*)d_in[8];
    const float* gw4 = (const float*)d_in[9];  const float* gb4 = (const float*)d_in[10];
    const float* gw5 = (const float*)d_in[11]; const float* gb5 = (const float*)d_in[12];
    const float* cw  = (const float*)d_in[13]; const float* cb  = (const float*)d_in[14];
    float* out = (float*)d_out;

    // ---- workspace layout (float offsets), ~150 MB ----
    float* W = (float*)d_ws;
    ushort_t* Xcl2h = (ushort_t*)(W);                 // [8][260][260][32] fp16 h
    ushort_t* Xcl4h = (ushort_t*)(W);                 // [8][130][130][128] fp16 h
    float*    Opart = W;                              // [4][8][128][4096] f32
    float*    lpart = W + 16777216;                   // [4][8][4096]
    ushort_t* Xcl3h = (ushort_t*)(W + 17305600);      // [8][132][132][64] fp16 h
    ushort_t* Vf    = (ushort_t*)(W + 17305600);      // [8][128][8][64][8] bf16 V-frags
    float*    s4   = W + 26226688;                    // [8][256][64][64] f32
    ushort_t* Fa   = (ushort_t*)(W + 26226688);       // [8][128][8][64][8] bf16 K-frags (aliases s4)
    ushort_t* Ft16 = (ushort_t*)(W + 30420992);       // [8][4096][128] bf16
    ushort_t* W2h = (ushort_t*)(W + 34615296);
    ushort_t* W2l = (ushort_t*)(W + 34640896);
    ushort_t* W3h = (ushort_t*)(W + 34666496);
    ushort_t* W3l = (ushort_t*)(W + 34768896);
    ushort_t* W4h = (ushort_t*)(W + 34871296);
    ushort_t* W4l = (ushort_t*)(W + 35018752);
    float* gate = W + 35166208;
    float* invn = W + 35198976;
    ushort_t* Xinh = (ushort_t*)(W + 35231744);       // [8][262][262][4] fp16 h + slack
    ushort_t* W1h  = (ushort_t*)(W + 37428416);       // [7][32][32] fp16
    ushort_t* W1l  = (ushort_t*)(W + 37432000);
    float* cwT = W + 37436416;                        // [128][256] f32 (131 KB)

    // ---- weight transforms + conv1 input prep ----
    transform_w_k<<<dim3(200),  256, 0, stream>>>(gw2, W2h, W2l, 64, 32, 25);
    transform_w_k<<<dim3(800),  256, 0, stream>>>(gw3, W3h, W3l, 128, 64, 25);
    transform_w_k<<<dim3(1152), 256, 0, stream>>>(gw4, W4h, W4l, 256, 128, 9);
    transform_w1_k<<<dim3(28), 256, 0, stream>>>(gw1, W1h, W1l);
    transform_cw_k<<<dim3(64), 256, 0, stream>>>(cw, cwT);
    prep_in_k<<<dim3(262, 8), 256, 0, stream>>>(imgs, masks, Xinh);

    // ---- conv stack (2-term split: weights h+l, activations h only) ----
    conv1_mfma_k<<<dim3(4, 256, 8), 256, 0, stream>>>(Xinh, W1h, W1l, gb1, Xcl2h);
    pad_cl_k<<<dim3(260, 8), 256, 0, stream>>>(Xcl2h, 260, 260, 2, 32, 256, 256);
    conv_mfma_k<5, 2, 32, 32, 64, 128, true><<<dim3(1, 128, 8), 256, 0, stream>>>(
        Xcl2h, W2h, W2l, gb2, 260, 260, 64, Xcl3h, 132, 132, 2, nullptr);
    pad_cl_k<<<dim3(132, 8), 256, 0, stream>>>(Xcl3h, 132, 132, 2, 64, 128, 128);
    conv3_mfma_k<<<dim3(1, 32, 16), 256, 0, stream>>>(Xcl3h, W3h, W3l, gb3, Xcl4h);
    pad_cl_k<<<dim3(130, 8), 256, 0, stream>>>(Xcl4h, 130, 130, 1, 128, 128, 128);
    conv_mfma_k<3, 2, 128, 32, 128, 64, false><<<dim3(1, 64, 16), 256, 0, stream>>>(
        Xcl4h, W4h, W4l, gb4, 130, 130, 256, nullptr, 0, 0, 0, s4);
    conv5_gate_k<<<dim3(64, 8), 256, 0, stream>>>(s4, gw5, gb5, gate);

    // ---- attention ----
    invn_k<<<dim3(16, 8), 256, 0, stream>>>(F, invn);
    prep_bf16_k<<<dim3(64, 8), 256, 0, stream>>>(F, Vf, Fa, Ft16);
    flash_attn_k<<<dim3(8, 256, 1), 64, 0, stream>>>(Ft16, Vf, Fa, invn, gate, Opart, lpart);
    combiner_k<<<dim3(16, 8, 4), 256, 0, stream>>>(Opart, lpart, F, cwT, cb, out);
}